// Round 8
// baseline (45.579 us; speedup 1.0000x reference)
//
#include <hip/hip_runtime.h>

#define NN 1024
#define EMBED 256
#define HID 128
#define EPS 1e-8f
#define NEPS (1.024e-5f)   // NN * EPS:  INV_N/(INV_N*r + EPS) == 1/(r + NN*EPS)
#define INV_N (1.0f / 1024.0f)
#define LDSPITCH 132  // 128 + 4: breaks power-of-2 LDS row stride, keeps 16B alignment

// ---------------------------------------------------------------------------
// Kernel A: hs' = source @ W1[:256] + b1 ; ht = target @ W1[256:]  (fp32)
// 256 blocks x 256 threads; blocks 0..3 also zero rowsum[1024]
// (replaces memset node; no tcol -- kCD reduces columns in-block).
// ---------------------------------------------------------------------------
__global__ __launch_bounds__(256) void kA(const float* __restrict__ src,
                                          const float* __restrict__ tgt,
                                          const float* __restrict__ W1,
                                          const float* __restrict__ b1,
                                          float* __restrict__ hsp,
                                          float* __restrict__ htp,
                                          float* __restrict__ zeroBuf) {
    __shared__ float s[8 * EMBED];  // 8 KB: 8 staged input rows
    const int b = blockIdx.x;
    const int tid = threadIdx.x;

    if (b < 4) zeroBuf[b * 256 + tid] = 0.0f;  // zero rowsum (1024 floats)

    const bool isSrc = (b < 128);
    const int r0 = (isSrc ? b : b - 128) * 8;
    const float* __restrict__ in = isSrc ? src : tgt;
    const float* __restrict__ w = W1 + (isSrc ? 0 : EMBED * HID);
    float* __restrict__ outp = isSrc ? hsp : htp;

    {   // stage 8 rows = 2048 floats = 512 float4
        const float4* g = (const float4*)(in + r0 * EMBED);
        float4* sv = (float4*)s;
        sv[tid] = g[tid];
        sv[tid + 256] = g[tid + 256];
    }
    __syncthreads();

    const int h = tid & 127;
    const int rr = tid >> 7;  // 0 or 1
    float acc0 = 0.f, acc1 = 0.f, acc2 = 0.f, acc3 = 0.f;

    for (int k = 0; k < EMBED; k += 4) {
        const float w0 = w[(k + 0) * HID + h];
        const float w1v = w[(k + 1) * HID + h];
        const float w2v = w[(k + 2) * HID + h];
        const float w3v = w[(k + 3) * HID + h];
        const float4 s0 = *(const float4*)&s[(rr + 0) * EMBED + k];
        const float4 s1 = *(const float4*)&s[(rr + 2) * EMBED + k];
        const float4 s2 = *(const float4*)&s[(rr + 4) * EMBED + k];
        const float4 s3 = *(const float4*)&s[(rr + 6) * EMBED + k];
        acc0 = fmaf(s0.x, w0, acc0); acc0 = fmaf(s0.y, w1v, acc0);
        acc0 = fmaf(s0.z, w2v, acc0); acc0 = fmaf(s0.w, w3v, acc0);
        acc1 = fmaf(s1.x, w0, acc1); acc1 = fmaf(s1.y, w1v, acc1);
        acc1 = fmaf(s1.z, w2v, acc1); acc1 = fmaf(s1.w, w3v, acc1);
        acc2 = fmaf(s2.x, w0, acc2); acc2 = fmaf(s2.y, w1v, acc2);
        acc2 = fmaf(s2.z, w2v, acc2); acc2 = fmaf(s2.w, w3v, acc2);
        acc3 = fmaf(s3.x, w0, acc3); acc3 = fmaf(s3.y, w1v, acc3);
        acc3 = fmaf(s3.z, w2v, acc3); acc3 = fmaf(s3.w, w3v, acc3);
    }

    const float bias = isSrc ? b1[h] : 0.0f;
    outp[(r0 + rr + 0) * HID + h] = acc0 + bias;
    outp[(r0 + rr + 2) * HID + h] = acc1 + bias;
    outp[(r0 + rr + 4) * HID + h] = acc2 + bias;
    outp[(r0 + rr + 6) * HID + h] = acc3 + bias;
}

// ---------------------------------------------------------------------------
// Kernel B: fused cost network + rowsum of K  (PROVEN f32 inner loop, R5).
//   C[i,j] = sum_h relu(hs'[i,h] + ht[j,h]) * W2[h] + b2
//   rowsum[i] += sum_j exp(-C[i,j])        (native exp in epilogue)
// 64x64 tile per block, 256 threads (16x16), 4x4 register blocking.
// ---------------------------------------------------------------------------
__global__ __launch_bounds__(256) void kB(const float* __restrict__ hsp,
                                          const float* __restrict__ htp,
                                          const float* __restrict__ W2,
                                          const float* __restrict__ b2,
                                          float* __restrict__ Cout,
                                          float* __restrict__ rowsum) {
    __shared__ float hsL[64 * LDSPITCH];  // 33 KB
    __shared__ float htL[64 * LDSPITCH];  // 33 KB
    __shared__ float w2L[HID];
    __shared__ float rsL[64];

    const int j0 = blockIdx.x * 64;
    const int i0 = blockIdx.y * 64;
    const int tid = threadIdx.x;

    for (int idx = tid; idx < 64 * 32; idx += 256) {
        const int i = idx >> 5;
        const int h4 = (idx & 31) << 2;
        *(float4*)&hsL[i * LDSPITCH + h4] = *(const float4*)&hsp[(i0 + i) * HID + h4];
        *(float4*)&htL[i * LDSPITCH + h4] = *(const float4*)&htp[(j0 + i) * HID + h4];
    }
    if (tid < HID) w2L[tid] = W2[tid];
    if (tid < 64) rsL[tid] = 0.0f;
    __syncthreads();

    const int ti = tid & 15;
    const int tj = tid >> 4;
    float acc[4][4] = {};

    for (int h = 0; h < HID; h += 4) {
        const float4 A0 = *(const float4*)&hsL[(ti + 0) * LDSPITCH + h];
        const float4 A1 = *(const float4*)&hsL[(ti + 16) * LDSPITCH + h];
        const float4 A2 = *(const float4*)&hsL[(ti + 32) * LDSPITCH + h];
        const float4 A3 = *(const float4*)&hsL[(ti + 48) * LDSPITCH + h];
        const float4 B0 = *(const float4*)&htL[(tj + 0) * LDSPITCH + h];
        const float4 B1 = *(const float4*)&htL[(tj + 16) * LDSPITCH + h];
        const float4 B2 = *(const float4*)&htL[(tj + 32) * LDSPITCH + h];
        const float4 B3 = *(const float4*)&htL[(tj + 48) * LDSPITCH + h];
        const float4 wv = *(const float4*)&w2L[h];
#define STEP(a, bb, Av, Bv)                                                    \
        {                                                                      \
            float t;                                                           \
            t = Av.x + Bv.x; acc[a][bb] = fmaf(fmaxf(t, 0.f), wv.x, acc[a][bb]); \
            t = Av.y + Bv.y; acc[a][bb] = fmaf(fmaxf(t, 0.f), wv.y, acc[a][bb]); \
            t = Av.z + Bv.z; acc[a][bb] = fmaf(fmaxf(t, 0.f), wv.z, acc[a][bb]); \
            t = Av.w + Bv.w; acc[a][bb] = fmaf(fmaxf(t, 0.f), wv.w, acc[a][bb]); \
        }
        STEP(0, 0, A0, B0) STEP(0, 1, A0, B1) STEP(0, 2, A0, B2) STEP(0, 3, A0, B3)
        STEP(1, 0, A1, B0) STEP(1, 1, A1, B1) STEP(1, 2, A1, B2) STEP(1, 3, A1, B3)
        STEP(2, 0, A2, B0) STEP(2, 1, A2, B1) STEP(2, 2, A2, B2) STEP(2, 3, A2, B3)
        STEP(3, 0, A3, B0) STEP(3, 1, A3, B1) STEP(3, 2, A3, B2) STEP(3, 3, A3, B3)
#undef STEP
    }

    const float b2v = b2[0];
    float rp[4] = {0.f, 0.f, 0.f, 0.f};
    for (int a = 0; a < 4; ++a) {
        const int i = i0 + ti + 16 * a;
        for (int bb = 0; bb < 4; ++bb) {
            const int j = j0 + tj + 16 * bb;
            const float c = acc[a][bb] + b2v;
            Cout[i * NN + j] = c;
            rp[a] += __expf(-c);
        }
    }
    for (int a = 0; a < 4; ++a) atomicAdd(&rsL[ti + 16 * a], rp[a]);
    __syncthreads();
    if (tid < 64) atomicAdd(&rowsum[i0 + tid], rsL[tid]);
}

// ---------------------------------------------------------------------------
// Kernel CD (fused): block owns 4 columns. Pass 1 computes p = exp(-C)*u for
// its 16 cells/thread (kept in registers) + column partial sums; LDS tree
// reduce (preserving tid%4 column classes) -> v[j]; pass 2 writes plan = p*v.
// No tcol, no global atomics, no second Cmat read, one fewer dispatch.
// ---------------------------------------------------------------------------
__global__ __launch_bounds__(256) void kCD(const float* __restrict__ Cmat,
                                           const float* __restrict__ rowsum,
                                           float* __restrict__ plan) {
    __shared__ float red[256];
    __shared__ float vL[4];
    const int j0 = blockIdx.x * 4;
    const int tid = threadIdx.x;
    const int jj = tid & 3;
    const int r = tid >> 2;       // 64 row-groups
    const int j = j0 + jj;

    float p[16];
    float ps = 0.f;
#pragma unroll
    for (int k = 0; k < 16; ++k) {
        const int i = r + 64 * k;
        const float u = __builtin_amdgcn_rcpf(rowsum[i] + NEPS);
        const float pk = __expf(-Cmat[i * NN + j]) * u;
        p[k] = pk;
        ps += pk;
    }
    red[tid] = ps;
    __syncthreads();
    // tree reduce preserving tid%4 (column) classes
    for (int s = 128; s >= 4; s >>= 1) {
        if (tid < s) red[tid] += red[tid + s];
        __syncthreads();
    }
    if (tid < 4) vL[tid] = INV_N * __builtin_amdgcn_rcpf(red[tid] + EPS);
    __syncthreads();
    const float v = vL[jj];
#pragma unroll
    for (int k = 0; k < 16; ++k) {
        plan[(r + 64 * k) * NN + j] = p[k] * v;
    }
}

// ---------------------------------------------------------------------------
extern "C" void kernel_launch(void* const* d_in, const int* in_sizes, int n_in,
                              void* d_out, int out_size, void* d_ws, size_t ws_size,
                              hipStream_t stream) {
    const float* src = (const float*)d_in[0];   // [1024, 256]
    const float* tgt = (const float*)d_in[1];   // [1024, 256]
    const float* W1  = (const float*)d_in[2];   // [512, 128]
    const float* b1  = (const float*)d_in[3];   // [128]
    const float* W2  = (const float*)d_in[4];   // [128, 1]
    const float* b2  = (const float*)d_in[5];   // [1]

    float* out = (float*)d_out;
    float* plan = out;            // [1024, 1024] (output 0)
    float* Cmat = out + NN * NN;  // [1024, 1024] (output 1)

    float* ws = (float*)d_ws;
    float* hsp    = ws;                 // [1024][128] f32
    float* htp    = ws + NN * HID;      // [1024][128] f32
    float* rowsum = ws + 2 * NN * HID;  // [1024], zeroed by kA blocks 0..3

    kA<<<256, 256, 0, stream>>>(src, tgt, W1, b1, hsp, htp, rowsum);
    kB<<<dim3(16, 16), 256, 0, stream>>>(hsp, htp, W2, b2, Cmat, rowsum);
    kCD<<<256, 256, 0, stream>>>(Cmat, rowsum, plan);
}

// Round 10
// 33.647 us; speedup vs baseline: 1.3546x; 1.3546x over previous
//
#include <hip/hip_runtime.h>

#define NN 1024
#define EMBED 256
#define HID 128
#define EPS 1e-8f
#define NEPS (1.024e-5f)   // NN * EPS:  INV_N/(INV_N*r + EPS) == 1/(r + NN*EPS)
#define INV_N (1.0f / 1024.0f)
#define PITCH_H 136    // halfs per LDS row: 272 B -> 16B-aligned rows, 2-way bank alias only

typedef _Float16 h2 __attribute__((ext_vector_type(2)));
typedef _Float16 h4f __attribute__((ext_vector_type(4)));
typedef unsigned int u32x4 __attribute__((ext_vector_type(4)));

// ---------------------------------------------------------------------------
// Kernel A: hs' = source @ W1[:256] + b1 ; ht = target @ W1[256:]  (fp32)
// 256 blocks x 256 threads; blocks 0..7 also zero rowsum[1024] ++ tcol[1024]
// (contiguous in ws) -- replaces the memset node.
// ---------------------------------------------------------------------------
__global__ __launch_bounds__(256) void kA(const float* __restrict__ src,
                                          const float* __restrict__ tgt,
                                          const float* __restrict__ W1,
                                          const float* __restrict__ b1,
                                          float* __restrict__ hsp,
                                          float* __restrict__ htp,
                                          float* __restrict__ zeroBuf) {
    __shared__ float s[8 * EMBED];  // 8 KB: 8 staged input rows
    const int b = blockIdx.x;
    const int tid = threadIdx.x;

    if (b < 8) zeroBuf[b * 256 + tid] = 0.0f;  // zero rowsum+tcol (2048 floats)

    const bool isSrc = (b < 128);
    const int r0 = (isSrc ? b : b - 128) * 8;
    const float* __restrict__ in = isSrc ? src : tgt;
    const float* __restrict__ w = W1 + (isSrc ? 0 : EMBED * HID);
    float* __restrict__ outp = isSrc ? hsp : htp;

    {   // stage 8 rows = 2048 floats = 512 float4
        const float4* g = (const float4*)(in + r0 * EMBED);
        float4* sv = (float4*)s;
        sv[tid] = g[tid];
        sv[tid + 256] = g[tid + 256];
    }
    __syncthreads();

    const int h = tid & 127;
    const int rr = tid >> 7;  // 0 or 1
    float acc0 = 0.f, acc1 = 0.f, acc2 = 0.f, acc3 = 0.f;

    for (int k = 0; k < EMBED; k += 4) {
        const float w0 = w[(k + 0) * HID + h];
        const float w1v = w[(k + 1) * HID + h];
        const float w2v = w[(k + 2) * HID + h];
        const float w3v = w[(k + 3) * HID + h];
        const float4 s0 = *(const float4*)&s[(rr + 0) * EMBED + k];
        const float4 s1 = *(const float4*)&s[(rr + 2) * EMBED + k];
        const float4 s2 = *(const float4*)&s[(rr + 4) * EMBED + k];
        const float4 s3 = *(const float4*)&s[(rr + 6) * EMBED + k];
        acc0 = fmaf(s0.x, w0, acc0); acc0 = fmaf(s0.y, w1v, acc0);
        acc0 = fmaf(s0.z, w2v, acc0); acc0 = fmaf(s0.w, w3v, acc0);
        acc1 = fmaf(s1.x, w0, acc1); acc1 = fmaf(s1.y, w1v, acc1);
        acc1 = fmaf(s1.z, w2v, acc1); acc1 = fmaf(s1.w, w3v, acc1);
        acc2 = fmaf(s2.x, w0, acc2); acc2 = fmaf(s2.y, w1v, acc2);
        acc2 = fmaf(s2.z, w2v, acc2); acc2 = fmaf(s2.w, w3v, acc2);
        acc3 = fmaf(s3.x, w0, acc3); acc3 = fmaf(s3.y, w1v, acc3);
        acc3 = fmaf(s3.z, w2v, acc3); acc3 = fmaf(s3.w, w3v, acc3);
    }

    const float bias = isSrc ? b1[h] : 0.0f;
    outp[(r0 + rr + 0) * HID + h] = acc0 + bias;
    outp[(r0 + rr + 2) * HID + h] = acc1 + bias;
    outp[(r0 + rr + 4) * HID + h] = acc2 + bias;
    outp[(r0 + rr + 6) * HID + h] = acc3 + bias;
}

// ---------------------------------------------------------------------------
// Kernel B: fused cost network + rowsum, packed-f16 math, F32 ACCUMULATION.
//   C[i,j] = sum_h relu(hs'[i,h] + ht[j,h]) * W2[h] + b2
// 64x64 tile, 256 threads (16x16), 4x4 register blocking. Per 2 h:
// v_pk_add_f16 + v_pk_max_f16 + v_dot2_f32_f16 (f32 acc) = 3 instr (was 6).
// f16 LDS tiles halve LDS traffic. Rows loaded as u32x4; each 32-bit lane
// bit_cast to h2 (shufflevector needs literal indices -- R9 compile fail).
// ---------------------------------------------------------------------------
__global__ __launch_bounds__(256) void kB(const float* __restrict__ hsp,
                                          const float* __restrict__ htp,
                                          const float* __restrict__ W2,
                                          const float* __restrict__ b2,
                                          float* __restrict__ Cout,
                                          float* __restrict__ rowsum) {
    __shared__ __align__(16) _Float16 hsL[64 * PITCH_H];  // 17.4 KB
    __shared__ __align__(16) _Float16 htL[64 * PITCH_H];  // 17.4 KB
    __shared__ __align__(16) _Float16 w2L[HID];
    __shared__ float rsL[64];

    const int j0 = blockIdx.x * 64;
    const int i0 = blockIdx.y * 64;
    const int tid = threadIdx.x;

    // stage + f32->f16 convert: 64 rows x 128 h per tile
    for (int idx = tid; idx < 64 * 32; idx += 256) {
        const int i = idx >> 5;
        const int h4 = (idx & 31) << 2;
        const float4 a = *(const float4*)&hsp[(i0 + i) * HID + h4];
        const float4 bv = *(const float4*)&htp[(j0 + i) * HID + h4];
        const h4f pa = {(_Float16)a.x, (_Float16)a.y, (_Float16)a.z, (_Float16)a.w};
        const h4f pb = {(_Float16)bv.x, (_Float16)bv.y, (_Float16)bv.z, (_Float16)bv.w};
        *(h4f*)&hsL[i * PITCH_H + h4] = pa;
        *(h4f*)&htL[i * PITCH_H + h4] = pb;
    }
    if (tid < HID) w2L[tid] = (_Float16)W2[tid];
    if (tid < 64) rsL[tid] = 0.0f;
    __syncthreads();

    const int ti = tid & 15;
    const int tj = tid >> 4;
    const h2 hz = {(_Float16)0.0f, (_Float16)0.0f};
    float acc[4][4] = {};

    for (int oct = 0; oct < 16; ++oct) {
        const int h = oct << 3;  // 8 h per iteration
        const u32x4 A0 = *(const u32x4*)&hsL[(ti + 0) * PITCH_H + h];
        const u32x4 A1 = *(const u32x4*)&hsL[(ti + 16) * PITCH_H + h];
        const u32x4 A2 = *(const u32x4*)&hsL[(ti + 32) * PITCH_H + h];
        const u32x4 A3 = *(const u32x4*)&hsL[(ti + 48) * PITCH_H + h];
        const u32x4 B0 = *(const u32x4*)&htL[(tj + 0) * PITCH_H + h];
        const u32x4 B1 = *(const u32x4*)&htL[(tj + 16) * PITCH_H + h];
        const u32x4 B2 = *(const u32x4*)&htL[(tj + 32) * PITCH_H + h];
        const u32x4 B3 = *(const u32x4*)&htL[(tj + 48) * PITCH_H + h];
        const u32x4 Wv = *(const u32x4*)&w2L[h];
#pragma unroll
        for (int q = 0; q < 4; ++q) {
            const h2 wq = __builtin_bit_cast(h2, (unsigned)Wv[q]);
            const h2 a0 = __builtin_bit_cast(h2, (unsigned)A0[q]);
            const h2 a1 = __builtin_bit_cast(h2, (unsigned)A1[q]);
            const h2 a2 = __builtin_bit_cast(h2, (unsigned)A2[q]);
            const h2 a3 = __builtin_bit_cast(h2, (unsigned)A3[q]);
            const h2 b0 = __builtin_bit_cast(h2, (unsigned)B0[q]);
            const h2 b1h = __builtin_bit_cast(h2, (unsigned)B1[q]);
            const h2 b2h = __builtin_bit_cast(h2, (unsigned)B2[q]);
            const h2 b3 = __builtin_bit_cast(h2, (unsigned)B3[q]);
#define CELL(x, y, av, bv)                                                     \
            {                                                                  \
                const h2 r = __builtin_elementwise_max((h2)((av) + (bv)), hz); \
                acc[x][y] = __builtin_amdgcn_fdot2(r, wq, acc[x][y], false);   \
            }
            CELL(0, 0, a0, b0) CELL(0, 1, a0, b1h) CELL(0, 2, a0, b2h) CELL(0, 3, a0, b3)
            CELL(1, 0, a1, b0) CELL(1, 1, a1, b1h) CELL(1, 2, a1, b2h) CELL(1, 3, a1, b3)
            CELL(2, 0, a2, b0) CELL(2, 1, a2, b1h) CELL(2, 2, a2, b2h) CELL(2, 3, a2, b3)
            CELL(3, 0, a3, b0) CELL(3, 1, a3, b1h) CELL(3, 2, a3, b2h) CELL(3, 3, a3, b3)
#undef CELL
        }
    }

    const float b2v = b2[0];
    float rp[4] = {0.f, 0.f, 0.f, 0.f};
#pragma unroll
    for (int a = 0; a < 4; ++a) {
        const int i = i0 + ti + 16 * a;
#pragma unroll
        for (int bb = 0; bb < 4; ++bb) {
            const int j = j0 + tj + 16 * bb;
            const float c = acc[a][bb] + b2v;
            Cout[i * NN + j] = c;
            rp[a] += __expf(-c);
        }
    }
    for (int a = 0; a < 4; ++a) atomicAdd(&rsL[ti + 16 * a], rp[a]);
    __syncthreads();
    if (tid < 64) atomicAdd(&rowsum[i0 + tid], rsL[tid]);
}

// ---------------------------------------------------------------------------
// Kernel C: t[j] = sum_i exp(-C[i,j]) * u[i],  u[i] = 1/(rowsum[i] + NN*EPS).
// (R5-proven) u precomputed per block into LDS; coalesced 256-col reads.
// ---------------------------------------------------------------------------
__global__ __launch_bounds__(256) void kC(const float* __restrict__ Cmat,
                                          const float* __restrict__ rowsum,
                                          float* __restrict__ tcol) {
    __shared__ float uL[16];
    const int b = blockIdx.x;
    const int jb = b & 3;
    const int ic = b >> 2;
    const int tid = threadIdx.x;
    if (tid < 16) {
        uL[tid] = __builtin_amdgcn_rcpf(rowsum[ic * 16 + tid] + NEPS);
    }
    __syncthreads();
    const int j = jb * 256 + tid;
    float acc = 0.f;
#pragma unroll
    for (int ii = 0; ii < 16; ++ii) {
        const float c = Cmat[(ic * 16 + ii) * NN + j];
        acc = fmaf(__expf(-c), uL[ii], acc);
    }
    atomicAdd(&tcol[j], acc);
}

// ---------------------------------------------------------------------------
// Kernel D: plan[i,j] = u[i] * exp(-C[i,j]) * v[j]  (R5-proven, coalesced)
// ---------------------------------------------------------------------------
__global__ __launch_bounds__(256) void kD(const float* __restrict__ Cmat,
                                          const float* __restrict__ rowsum,
                                          const float* __restrict__ tcol,
                                          float* __restrict__ plan) {
    const int i0 = blockIdx.x * 4;
    const int tid = threadIdx.x;
    const int j4 = tid * 4;
    const float4 t4 = *(const float4*)&tcol[j4];
    float4 v4;
    v4.x = INV_N * __builtin_amdgcn_rcpf(t4.x + EPS);
    v4.y = INV_N * __builtin_amdgcn_rcpf(t4.y + EPS);
    v4.z = INV_N * __builtin_amdgcn_rcpf(t4.z + EPS);
    v4.w = INV_N * __builtin_amdgcn_rcpf(t4.w + EPS);
#pragma unroll
    for (int r = 0; r < 4; ++r) {
        const int row = i0 + r;
        const float u = __builtin_amdgcn_rcpf(rowsum[row] + NEPS);
        const float4 c4 = *(const float4*)&Cmat[row * NN + j4];
        float4 p;
        p.x = u * __expf(-c4.x) * v4.x;
        p.y = u * __expf(-c4.y) * v4.y;
        p.z = u * __expf(-c4.z) * v4.z;
        p.w = u * __expf(-c4.w) * v4.w;
        *(float4*)&plan[row * NN + j4] = p;
    }
}

// ---------------------------------------------------------------------------
extern "C" void kernel_launch(void* const* d_in, const int* in_sizes, int n_in,
                              void* d_out, int out_size, void* d_ws, size_t ws_size,
                              hipStream_t stream) {
    const float* src = (const float*)d_in[0];   // [1024, 256]
    const float* tgt = (const float*)d_in[1];   // [1024, 256]
    const float* W1  = (const float*)d_in[2];   // [512, 128]
    const float* b1  = (const float*)d_in[3];   // [128]
    const float* W2  = (const float*)d_in[4];   // [128, 1]
    const float* b2  = (const float*)d_in[5];   // [1]

    float* out = (float*)d_out;
    float* plan = out;            // [1024, 1024] (output 0)
    float* Cmat = out + NN * NN;  // [1024, 1024] (output 1)

    float* ws = (float*)d_ws;
    float* hsp    = ws;                 // [1024][128] f32
    float* htp    = ws + NN * HID;      // [1024][128] f32
    float* rowsum = ws + 2 * NN * HID;  // [1024]
    float* tcol   = rowsum + NN;        // [1024]
    // rowsum & tcol (contiguous 2048 floats) zeroed by kA blocks 0..7.

    kA<<<256, 256, 0, stream>>>(src, tgt, W1, b1, hsp, htp, rowsum);
    kB<<<dim3(16, 16), 256, 0, stream>>>(hsp, htp, W2, b2, Cmat, rowsum);
    kC<<<256, 256, 0, stream>>>(Cmat, rowsum, tcol);
    kD<<<256, 256, 0, stream>>>(Cmat, rowsum, tcol, plan);
}